// Round 5
// baseline (181.574 us; speedup 1.0000x reference)
//
#include <hip/hip_runtime.h>
#include <cstddef>

namespace {
constexpr int cB = 64, cN = 34, cF = 16, cT = 96, cK = 3, cO = 64;
constexpr int TT = 4;     // t-tile per block
constexpr int LP = 68;    // u16 pitch, 34-row matrices (136B rows -> 2-way-free banks)
constexpr int HP = 84;    // u16 pitch for H (168B rows, 2-way-free, 8B-aligned frags)
constexpr int HR = 146;   // 144 used H rows + overrun pad
constexpr float cEPS = 1e-8f;

typedef __attribute__((ext_vector_type(8))) _Float16 f16x8;
typedef __attribute__((ext_vector_type(8))) short   s16x8;
typedef __attribute__((ext_vector_type(4))) float   f32x4;

__device__ inline unsigned short f2h(float v) {
    _Float16 h = (_Float16)v;
    return __builtin_bit_cast(unsigned short, h);
}
__device__ inline float h2f(unsigned short u) {
    return (float)__builtin_bit_cast(_Float16, u);
}
}

// ---------------- softmax over axis=2 (i) of st_attention (B,K,N,N) ----------------
__global__ __launch_bounds__(256) void att_softmax_k(const float* __restrict__ st,
                                                     float* __restrict__ att) {
    int idx = blockIdx.x * blockDim.x + threadIdx.x;
    if (idx >= cB * cK * cN) return;
    int j = idx % cN;
    int bk = idx / cN;
    const float* base = st + (size_t)bk * cN * cN + j;
    float v[cN];
    float m = -3.402823466e38f;
#pragma unroll
    for (int i = 0; i < cN; ++i) { v[i] = base[(size_t)i * cN]; m = fmaxf(m, v[i]); }
    float s = 0.f;
#pragma unroll
    for (int i = 0; i < cN; ++i) { v[i] = __expf(v[i] - m); s += v[i]; }
    float inv = 1.f / s;
    float* ob = att + (size_t)bk * cN * cN + j;
#pragma unroll
    for (int i = 0; i < cN; ++i) ob[(size_t)i * cN] = v[i] * inv;
}

// ---------------- main: one block per (b, 4-t tile); fp16 MFMA pipeline ----------------
__global__ __launch_bounds__(256, 6) void cheb_main_k(
    const float* __restrict__ x,      // (B,N,F,T)
    const float* __restrict__ att,    // (B,K,N,N) softmaxed
    const float* __restrict__ pos,    // (N,2)
    const float* __restrict__ dist,   // (N,N)
    const float* __restrict__ Th,     // (K,F,O)
    const float* __restrict__ ThL,    // (K,F,O)
    float* __restrict__ out)          // (B,N,O,T)
{
    // fp16 matrices [34][LP]; cols >=34 zero (k-pad). Order matters: A-operand
    // row-overrun reads (rows 34..47) land in the next array (finite, D-rows discarded).
    __shared__ __align__(16) unsigned short s_L1[cN * LP];  // A(fp32) overlay; L1; then M2T
    __shared__ __align__(16) unsigned short s_L2[cN * LP];  // L2; then M4T
    __shared__ __align__(16) unsigned short s_M1T[cN * LP]; // att1 .* L1^T
    __shared__ __align__(16) unsigned short s_M3T[cN * LP]; // att1 .* L2^T
    __shared__ __align__(16) unsigned short s_gsT[cF * LP]; // gs^T fp16
    __shared__ __align__(16) unsigned short s_H[HR * HP];   // fp16 H, row = 4*j + tt
    __shared__ float s_d0[cN], s_v1[cN], s_v2[cN], s_p1[cN], s_p2[cN], s_di1[cN], s_di2[cN];

    const int tid = threadIdx.x;
    const int lane = tid & 63;
    const int w = tid >> 6;
    const int lr = lane & 15;    // tile row/col index
    const int lg = lane >> 4;    // k-group
    const int kb8 = lg * 8;
    const int ocol = w * 16 + lr;

    // XCD swizzle (grid 1536, %8==0 -> bijective)
    const unsigned g = blockIdx.x;
    const unsigned lin = (g & 7u) * (cB * (cT / TT) / 8) + (g >> 3);
    const int b = lin / (cT / TT);
    const int t0 = (lin % (cT / TT)) * TT;

    // ---- Theta B-fragments fp16 (c = p*16+f; p0 = Th0+ThL0 merged) ----
    f16x8 bfr[3];
#pragma unroll
    for (int s = 0; s < 3; ++s) {
#pragma unroll
        for (int j = 0; j < 8; ++j) {
            int cc = 32 * s + kb8 + j;
            float v = 0.f;
            if (cc < 80) {
                int p = cc >> 4, f = cc & 15;
                if (p == 0)      v = Th[f * cO + ocol] + ThL[f * cO + ocol];
                else if (p == 1) v = Th[(cF + f) * cO + ocol];
                else if (p == 2) v = Th[(2 * cF + f) * cO + ocol];
                else if (p == 3) v = ThL[(cF + f) * cO + ocol];
                else             v = ThL[(2 * cF + f) * cO + ocol];
            }
            bfr[s][j] = (_Float16)v;
        }
    }

    // ---- block init: zero LDS pads, stage d0/p-hat ----
    {
        f32x4 z = (f32x4){0.f, 0.f, 0.f, 0.f};
        for (int i2 = tid; i2 < cN * LP / 8; i2 += 256) {
            ((f32x4*)s_L1)[i2] = z; ((f32x4*)s_L2)[i2] = z;
            ((f32x4*)s_M1T)[i2] = z; ((f32x4*)s_M3T)[i2] = z;
        }
        for (int i2 = tid; i2 < cF * LP / 8; i2 += 256) ((f32x4*)s_gsT)[i2] = z;
        for (int i2 = tid; i2 < HR * HP / 2; i2 += 256) ((unsigned*)s_H)[i2] = 0u;
        if (tid < cN) {
            float px = pos[2 * tid], py = pos[2 * tid + 1];
            float pn = sqrtf(px * px + py * py);
            float r = 1.f / fmaxf(pn, cEPS);
            s_p1[tid] = px * r; s_p2[tid] = py * r;
            s_d0[tid] = att[((size_t)b * cK) * cN * cN + tid * cN + tid];
        }
    }
    __syncthreads();

    const float* att1 = att + ((size_t)b * cK + 1) * cN * cN;
    const float* att2 = att + ((size_t)b * cK + 2) * cN * cN;

    for (int tt = 0; tt < TT; ++tt) {
        const int t = t0 + tt;

        // ---- P1: stage v' (vn-folded) and gsT fp16 ----
        if (tid < cN) {
            float x1 = x[(((size_t)b * cN + tid) * cF + 1) * cT + t];
            float x2 = x[(((size_t)b * cN + tid) * cF + 2) * cT + t];
            float vn = sqrtf(x1 * x1 + x2 * x2);
            float s = vn / fmaxf(vn, cEPS);
            s_v1[tid] = x1 * s; s_v2[tid] = x2 * s;
        }
        for (int idx = tid; idx < cN * cF; idx += 256) {
            int n = idx >> 4, f = idx & 15;
            s_gsT[f * LP + n] = f2h(x[(((size_t)b * cN + n) * cF + f) * cT + t]);
        }
        __syncthreads();

        // ---- P2: adjacency A fp32 (compact 34x34) into s_L1 bytes ----
        float* Af = (float*)s_L1;
#pragma unroll
        for (int e = 0; e < 5; ++e) {
            int idx = tid + 256 * e;
            if (idx < cN * cN) {
                int i = idx / cN, m = idx - i * cN;
                float dot = s_v1[i] * s_p1[m] + s_v2[i] * s_p2[m];
                Af[idx] = __fdividef(fmaxf(dot, 0.f), dist[idx]);
            }
        }
        __syncthreads();

        // ---- P2b: degrees; P3a: stash A pairs in regs before overwrite ----
        if (tid < cN) {
            float s = 0.f;
#pragma unroll
            for (int m = 0; m < cN; ++m) s += Af[tid * cN + m];
            s_di1[tid] = (s > 0.f) ? rsqrtf(fmaxf(s, 1e-12f)) : 0.f;
        } else if (tid >= 64 && tid < 64 + cN) {
            int j = tid - 64;
            float s = 0.f;
#pragma unroll
            for (int i = 0; i < cN; ++i) s += Af[i * cN + j];
            s_di2[j] = (s > 0.f) ? rsqrtf(fmaxf(s, 1e-12f)) : 0.f;
        }
        float aij[5], aji[5];
#pragma unroll
        for (int e = 0; e < 5; ++e) {
            int idx = tid + 256 * e;
            if (idx < cN * cN) {
                int i = idx / cN, j = idx - i * cN;
                aij[e] = Af[idx];
                aji[e] = Af[j * cN + i];
            }
        }
        __syncthreads();

        // ---- P3b: L1/L2 fp16 (+ re-zero L1 pad cols), M1T/M3T = att1.*L^T ----
#pragma unroll
        for (int e = 0; e < 5; ++e) {
            int idx = tid + 256 * e;
            if (idx < cN * cN) {
                int i = idx / cN, j = idx - i * cN;
                float diag = (i == j) ? 1.f : 0.f;
                float l1 = diag - s_di1[i] * aij[e] * s_di1[j];
                float l2 = diag - s_di2[i] * aji[e] * s_di2[j];
                int rm = i * LP + j;
                s_L1[rm] = f2h(l1);
                s_L1[rm + cN] = 0;  // re-zero pad col dirtied by fp32-A overlay
                s_L2[rm] = f2h(l2);
                float a1 = att1[idx];
                int tm = j * LP + i;
                s_M1T[tm] = f2h(a1 * l1);
                s_M3T[tm] = f2h(a1 * l2);
            }
        }
        __syncthreads();

        // ---- P4: C = L@L via fp16 MFMA; wave: mat = w>>1, col-tiles split ----
        const unsigned short* Ah = (w < 2) ? s_L1 : s_L2;
        const int nnt = (w & 1) ? 1 : 2;
        const int ntb0 = (w & 1) ? 32 : 0;
        f32x4 cd0[3], cd1[3];
#pragma unroll
        for (int mt = 0; mt < 3; ++mt) {
            cd0[mt] = (f32x4){0.f, 0.f, 0.f, 0.f};
            cd1[mt] = (f32x4){0.f, 0.f, 0.f, 0.f};
        }
#pragma unroll
        for (int ks = 0; ks < 2; ++ks) {
            f16x8 fah[3];
#pragma unroll
            for (int mt = 0; mt < 3; ++mt)
                fah[mt] = *(const f16x8*)&Ah[(mt * 16 + lr) * LP + 32 * ks + kb8];
#pragma unroll
            for (int un = 0; un < 2; ++un) {
                if (un == 1 && nnt < 2) break;
                int col = ntb0 + un * 16 + lr;
                s16x8 fbb;
#pragma unroll
                for (int e2 = 0; e2 < 8; ++e2) {
                    int kk = 32 * ks + kb8 + e2;
                    fbb[e2] = (kk < cN) ? (short)Ah[kk * LP + col] : (short)0;
                }
                f16x8 fb = __builtin_bit_cast(f16x8, fbb);
#pragma unroll
                for (int mt = 0; mt < 3; ++mt) {
                    f32x4 acc = un ? cd1[mt] : cd0[mt];
                    acc = __builtin_amdgcn_mfma_f32_16x16x32_f16(fah[mt], fb, acc, 0, 0, 0);
                    if (un) cd1[mt] = acc; else cd0[mt] = acc;
                }
            }
        }
        __syncthreads();  // all L reads done before M2T/M4T overlay writes

        // ---- P5: M2T = att2 .* (2C1 - I) into s_L1; M4T into s_L2 ----
        {
            unsigned short* Md = (w < 2) ? s_L1 : s_L2;
#pragma unroll
            for (int un = 0; un < 2; ++un) {
                if (un == 1 && nnt < 2) break;
                int jb = ntb0 + un * 16 + lr;  // C col = j index
                if (jb < cN) {
#pragma unroll
                    for (int mt = 0; mt < 3; ++mt) {
#pragma unroll
                        for (int r = 0; r < 4; ++r) {
                            int i = mt * 16 + lg * 4 + r;
                            if (i < cN) {
                                float dv = un ? cd1[mt][r] : cd0[mt][r];
                                float cv = 2.f * dv - ((i == jb) ? 1.f : 0.f);
                                Md[jb * LP + i] = f2h(att2[i * cN + jb] * cv);
                            }
                        }
                    }
                }
            }
        }
        __syncthreads();

        // ---- P6: H_p = M_p^T @ gs via MFMA (wave w -> p = w+1), + p0 diag block ----
        {
            const unsigned short* Ap = (w == 0) ? s_M1T : (w == 1) ? s_L1
                                     : (w == 2) ? s_M3T : s_L2;
            f32x4 hd[3];
#pragma unroll
            for (int mt = 0; mt < 3; ++mt) hd[mt] = (f32x4){0.f, 0.f, 0.f, 0.f};
#pragma unroll
            for (int ks = 0; ks < 2; ++ks) {
                f16x8 fb = *(const f16x8*)&s_gsT[lr * LP + 32 * ks + kb8];
#pragma unroll
                for (int mt = 0; mt < 3; ++mt) {
                    f16x8 fa = *(const f16x8*)&Ap[(mt * 16 + lr) * LP + 32 * ks + kb8];
                    hd[mt] = __builtin_amdgcn_mfma_f32_16x16x32_f16(fa, fb, hd[mt], 0, 0, 0);
                }
            }
            int pc = 16 * (w + 1);
#pragma unroll
            for (int mt = 0; mt < 3; ++mt) {
#pragma unroll
                for (int r = 0; r < 4; ++r) {
                    int j = mt * 16 + lg * 4 + r;
                    if (j < cN)
                        s_H[(4 * j + tt) * HP + pc + lr] = f2h(hd[mt][r]);
                }
            }
            int j0 = w * 9;
            int jn = (j0 + 9 <= cN) ? 9 : (cN - j0);
            for (int idx = lane; idx < jn * 16; idx += 64) {
                int j = j0 + (idx >> 4), f = idx & 15;
                s_H[(4 * j + tt) * HP + f] = f2h(s_d0[j] * h2f(s_gsT[f * LP + j]));
            }
        }
        __syncthreads();
    }

    // ---- P7: out = relu(H @ Thcat); rows 4j+tt give float4-over-t stores ----
    f32x4 acc[9];
#pragma unroll
    for (int mt = 0; mt < 9; ++mt) acc[mt] = (f32x4){0.f, 0.f, 0.f, 0.f};
#pragma unroll
    for (int s = 0; s < 3; ++s) {
#pragma unroll
        for (int mt = 0; mt < 9; ++mt) {
            f16x8 a = *(const f16x8*)&s_H[(mt * 16 + lr) * HP + kb8 + 32 * s];
            acc[mt] = __builtin_amdgcn_mfma_f32_16x16x32_f16(a, bfr[s], acc[mt], 0, 0, 0);
        }
    }
#pragma unroll
    for (int mt = 0; mt < 9; ++mt) {
        int j = 4 * mt + lg;
        if (j < cN) {
            float4 v;
            v.x = fmaxf(acc[mt][0], 0.f);
            v.y = fmaxf(acc[mt][1], 0.f);
            v.z = fmaxf(acc[mt][2], 0.f);
            v.w = fmaxf(acc[mt][3], 0.f);
            *(float4*)&out[(((size_t)b * cN + j) * cO + ocol) * cT + t0] = v;
        }
    }
}

extern "C" void kernel_launch(void* const* d_in, const int* in_sizes, int n_in,
                              void* d_out, int out_size, void* d_ws, size_t ws_size,
                              hipStream_t stream) {
    const float* x    = (const float*)d_in[0];
    const float* st   = (const float*)d_in[1];
    const float* pos  = (const float*)d_in[2];
    const float* dist = (const float*)d_in[3];
    const float* Th   = (const float*)d_in[4];
    const float* ThL  = (const float*)d_in[5];
    float* out = (float*)d_out;
    float* att = (float*)d_ws;  // B*K*N*N floats = 888 KB

    att_softmax_k<<<(cB * cK * cN + 255) / 256, 256, 0, stream>>>(st, att);
    cheb_main_k<<<cB * (cT / TT), 256, 0, stream>>>(x, att, pos, dist, Th, ThL, out);
}

// Round 8
// 97.382 us; speedup vs baseline: 1.8645x; 1.8645x over previous
//
#include <hip/hip_runtime.h>
#include <cstddef>

namespace {
constexpr int cB = 64, cN = 34, cF = 16, cT = 96, cK = 3, cO = 64;
constexpr int LP = 72;    // u16 pitch (144B rows: 16B-aligned frags, 2-way-free banks)
constexpr int HPA = 80;   // kernel-A H staging pitch (copy-only, 40 dwords)
constexpr int BHP = 88;   // kernel-B H pitch (176B rows: 16B-aligned, 2-way-free)
constexpr int T4 = cT / 4;
constexpr float cEPS = 1e-8f;

typedef __attribute__((ext_vector_type(8))) _Float16 f16x8;
typedef __attribute__((ext_vector_type(8))) short   s16x8;
typedef __attribute__((ext_vector_type(4))) float   f32x4;

__device__ inline unsigned short f2h(float v) {
    _Float16 h = (_Float16)v;
    return __builtin_bit_cast(unsigned short, h);
}
__device__ inline float h2f(unsigned short u) {
    return (float)__builtin_bit_cast(_Float16, u);
}

// H staging address inside d_out (dword index). s = tt*40 + c, s < 160.
// Slots for tile (b,t4) live only in out[:, o<40, 4*t4 .. 4*t4+3] -> each proj_k
// block reads exactly the slots its own final stores later overwrite: race-free.
__device__ inline size_t hstage_idx(int b, int t4, int j, int s) {
    return (((size_t)b * cN + j) * cO + (s >> 2)) * cT + 4 * t4 + (s & 3);
}
}

// ---------------- softmax over axis=2 (i) of st_attention (B,K,N,N) ----------------
__global__ __launch_bounds__(256) void att_softmax_k(const float* __restrict__ st,
                                                     float* __restrict__ att) {
    int idx = blockIdx.x * blockDim.x + threadIdx.x;
    if (idx >= cB * cK * cN) return;
    int j = idx % cN;
    int bk = idx / cN;
    const float* base = st + (size_t)bk * cN * cN + j;
    float v[cN];
    float m = -3.402823466e38f;
#pragma unroll
    for (int i = 0; i < cN; ++i) { v[i] = base[(size_t)i * cN]; m = fmaxf(m, v[i]); }
    float s = 0.f;
#pragma unroll
    for (int i = 0; i < cN; ++i) { v[i] = __expf(v[i] - m); s += v[i]; }
    float inv = 1.f / s;
    float* ob = att + (size_t)bk * cN * cN + j;
#pragma unroll
    for (int i = 0; i < cN; ++i) ob[(size_t)i * cN] = v[i] * inv;
}

// ---------------- kernel A: one block per (b,t); H(34x80 fp16) -> staged in out ----------------
__global__ __launch_bounds__(256, 4) void cheb_h_k(
    const float* __restrict__ x,      // (B,N,F,T)
    const float* __restrict__ att,    // (B,K,N,N) softmaxed
    const float* __restrict__ pos,    // (N,2)
    const float* __restrict__ dist,   // (N,N)
    unsigned* __restrict__ Hst)       // = (unsigned*)out, staging slots
{
    // adjacency fp32 overlays s_L1; A-frag row-overrun reads (rows 34..47) land in
    // the NEXT array (finite garbage feeding discarded D-rows); order matters.
    __shared__ __align__(16) unsigned short s_L1[cN * LP];   // A fp32 overlay; L1; then M2T
    __shared__ __align__(16) unsigned short s_L2[cN * LP];   // L2; then M4T
    __shared__ __align__(16) unsigned short s_M1T[cN * LP];  // att1 .* L1, transposed
    __shared__ __align__(16) unsigned short s_M3T[cN * LP];  // att1 .* L2, transposed
    __shared__ __align__(16) unsigned short s_gsT[cF * LP];  // gs^T fp16
    __shared__ __align__(16) unsigned short s_H[cN * HPA];   // H staging
    __shared__ float s_d0[cN], s_v1[cN], s_v2[cN], s_p1[cN], s_p2[cN], s_di1[cN], s_di2[cN];

    const int tid = threadIdx.x;
    const int lane = tid & 63;
    const int w = tid >> 6;
    const int lr = lane & 15;
    const int lg = lane >> 4;
    const int kb8 = lg * 8;

    // XCD swizzle (grid 6144, %8==0 -> bijective)
    const unsigned g = blockIdx.x;
    const unsigned lin = (g & 7u) * (cB * cT / 8) + (g >> 3);
    const int b = lin / cT, t = lin % cT;

    // ---- init: zero matrix pads, stage p-hat/d0/v'/gsT ----
    // NOTE: s_gsT is NOT in the zero loop — its single-writer fill below covers
    // data cells (n<34) AND pad cells (n>=34). (Rounds 6/7 bug: zero loop raced
    // with the data fill in this same pre-barrier region.)
    for (int i2 = tid; i2 < cN * LP / 2; i2 += 256) {
        ((unsigned*)s_L1)[i2] = 0u; ((unsigned*)s_L2)[i2] = 0u;
        ((unsigned*)s_M1T)[i2] = 0u; ((unsigned*)s_M3T)[i2] = 0u;
    }
    if (tid < cN) {
        float px = pos[2 * tid], py = pos[2 * tid + 1];
        float pn = sqrtf(px * px + py * py);
        float r = 1.f / fmaxf(pn, cEPS);
        s_p1[tid] = px * r; s_p2[tid] = py * r;
        s_d0[tid] = att[((size_t)b * cK) * cN * cN + tid * cN + tid];
    } else if (tid >= 64 && tid < 64 + cN) {
        int n = tid - 64;
        float x1 = x[(((size_t)b * cN + n) * cF + 1) * cT + t];
        float x2 = x[(((size_t)b * cN + n) * cF + 2) * cT + t];
        float vn = sqrtf(x1 * x1 + x2 * x2);
        float s = vn / fmaxf(vn, cEPS);
        s_v1[n] = x1 * s; s_v2[n] = x2 * s;
    }
    for (int idx = tid; idx < cF * LP; idx += 256) {
        int f = idx / LP, n = idx - f * LP;
        unsigned short v = 0;
        if (n < cN) v = f2h(x[(((size_t)b * cN + n) * cF + f) * cT + t]);
        s_gsT[idx] = v;
    }
    __syncthreads();  // b1

    // ---- P2: adjacency A fp32 (compact 34x34) over s_L1 bytes ----
    float* Af = (float*)s_L1;
#pragma unroll
    for (int e = 0; e < 5; ++e) {
        int idx = tid + 256 * e;
        if (idx < cN * cN) {
            int i = idx / cN, m = idx - i * cN;
            float dot = s_v1[i] * s_p1[m] + s_v2[i] * s_p2[m];
            Af[idx] = __fdividef(fmaxf(dot, 0.f), dist[idx]);
        }
    }
    __syncthreads();  // b2

    // ---- P2b: degrees + stash A pairs in regs ----
    if (tid < cN) {
        float s = 0.f;
#pragma unroll
        for (int m = 0; m < cN; ++m) s += Af[tid * cN + m];
        s_di1[tid] = (s > 0.f) ? rsqrtf(fmaxf(s, 1e-12f)) : 0.f;
    } else if (tid >= 64 && tid < 64 + cN) {
        int j = tid - 64;
        float s = 0.f;
#pragma unroll
        for (int i = 0; i < cN; ++i) s += Af[i * cN + j];
        s_di2[j] = (s > 0.f) ? rsqrtf(fmaxf(s, 1e-12f)) : 0.f;
    }
    float aij[5], aji[5];
#pragma unroll
    for (int e = 0; e < 5; ++e) {
        int idx = tid + 256 * e;
        if (idx < cN * cN) {
            int i = idx / cN, j = idx - i * cN;
            aij[e] = Af[idx];
            aji[e] = Af[j * cN + i];
        }
    }
    __syncthreads();  // b3

    // ---- P3: L1/L2 fp16 (re-zero pads dirtied by fp32-A), M1T/M3T = att1.*L^T ----
    const float* att1 = att + ((size_t)b * cK + 1) * cN * cN;
    const float* att2 = att + ((size_t)b * cK + 2) * cN * cN;
#pragma unroll
    for (int e = 0; e < 5; ++e) {
        int idx = tid + 256 * e;
        if (idx < cN * cN) {
            int i = idx / cN, j = idx - i * cN;
            float diag = (i == j) ? 1.f : 0.f;
            float l1 = diag - s_di1[i] * aij[e] * s_di1[j];
            float l2 = diag - s_di2[i] * aji[e] * s_di2[j];
            int rm = i * LP + j, tm = j * LP + i;
            s_L1[rm] = f2h(l1);
            s_L1[rm + cN] = 0;                       // pad cols 34..67
            if (j < 4) s_L1[i * LP + 68 + j] = 0;    // pad cols 68..71
            s_L2[rm] = f2h(l2);
            float a1 = att1[idx];
            s_M1T[tm] = f2h(a1 * l1);
            s_M3T[tm] = f2h(a1 * l2);
        }
    }
    __syncthreads();  // b4

    // ---- P4: C = L@L fp16 MFMA (round-5-validated predicated-scalar B build) ----
    const unsigned short* Ah = (w < 2) ? s_L1 : s_L2;
    const int nnt = (w & 1) ? 1 : 2;
    const int ntb0 = (w & 1) ? 32 : 0;
    f32x4 cd0[3], cd1[3];
#pragma unroll
    for (int mt = 0; mt < 3; ++mt) {
        cd0[mt] = (f32x4){0.f, 0.f, 0.f, 0.f};
        cd1[mt] = (f32x4){0.f, 0.f, 0.f, 0.f};
    }
#pragma unroll
    for (int ks = 0; ks < 2; ++ks) {
        f16x8 fah[3];
#pragma unroll
        for (int mt = 0; mt < 3; ++mt)
            fah[mt] = *(const f16x8*)&Ah[(mt * 16 + lr) * LP + 32 * ks + kb8];
#pragma unroll
        for (int un = 0; un < 2; ++un) {
            if (un == 1 && nnt < 2) break;
            int col = ntb0 + un * 16 + lr;
            s16x8 fbb;
#pragma unroll
            for (int e2 = 0; e2 < 8; ++e2) {
                int kk = 32 * ks + kb8 + e2;
                fbb[e2] = (kk < cN) ? (short)Ah[kk * LP + col] : (short)0;
            }
            f16x8 fb = __builtin_bit_cast(f16x8, fbb);
#pragma unroll
            for (int mt = 0; mt < 3; ++mt) {
                f32x4 acc = un ? cd1[mt] : cd0[mt];
                acc = __builtin_amdgcn_mfma_f32_16x16x32_f16(fah[mt], fb, acc, 0, 0, 0);
                if (un) cd1[mt] = acc; else cd0[mt] = acc;
            }
        }
    }
    __syncthreads();  // b5: all L reads done before M2T/M4T overlay writes

    // ---- P5: M2T = att2 .* (2C1 - I) into s_L1; M4T into s_L2 ----
    {
        unsigned short* Md = (w < 2) ? s_L1 : s_L2;
#pragma unroll
        for (int un = 0; un < 2; ++un) {
            if (un == 1 && nnt < 2) break;
            int jb = ntb0 + un * 16 + lr;
            if (jb < cN) {
#pragma unroll
                for (int mt = 0; mt < 3; ++mt) {
#pragma unroll
                    for (int r = 0; r < 4; ++r) {
                        int i = mt * 16 + lg * 4 + r;
                        if (i < cN) {
                            float dv = un ? cd1[mt][r] : cd0[mt][r];
                            float cv = 2.f * dv - ((i == jb) ? 1.f : 0.f);
                            Md[jb * LP + i] = f2h(att2[i * cN + jb] * cv);
                        }
                    }
                }
            }
        }
    }
    __syncthreads();  // b6

    // ---- P6: H_p = M_p^T @ gs (wave w -> p=w+1); p0 diag block by all threads ----
    {
        const unsigned short* Ap = (w == 0) ? s_M1T : (w == 1) ? s_L1
                                 : (w == 2) ? s_M3T : s_L2;
        f32x4 hd[3];
#pragma unroll
        for (int mt = 0; mt < 3; ++mt) hd[mt] = (f32x4){0.f, 0.f, 0.f, 0.f};
#pragma unroll
        for (int ks = 0; ks < 2; ++ks) {
            f16x8 fb = *(const f16x8*)&s_gsT[lr * LP + 32 * ks + kb8];
#pragma unroll
            for (int mt = 0; mt < 3; ++mt) {
                f16x8 fa = *(const f16x8*)&Ap[(mt * 16 + lr) * LP + 32 * ks + kb8];
                hd[mt] = __builtin_amdgcn_mfma_f32_16x16x32_f16(fa, fb, hd[mt], 0, 0, 0);
            }
        }
        int pc = 16 * (w + 1);
#pragma unroll
        for (int mt = 0; mt < 3; ++mt) {
#pragma unroll
            for (int r = 0; r < 4; ++r) {
                int j = mt * 16 + lg * 4 + r;
                if (j < cN) s_H[j * HPA + pc + lr] = f2h(hd[mt][r]);
            }
        }
    }
    for (int idx = tid; idx < cN * cF; idx += 256) {
        int j = idx >> 4, f = idx & 15;
        s_H[j * HPA + f] = f2h(s_d0[j] * h2f(s_gsT[f * LP + j]));
    }
    __syncthreads();  // b7

    // ---- copy H -> staging slots in out (16B runs; own (b,t) slots only) ----
    {
        const unsigned* src = (const unsigned*)s_H;
        const int t4 = t >> 2, tt = t & 3;
        for (int i2 = tid; i2 < cN * (HPA / 2); i2 += 256) {
            int j = i2 / (HPA / 2), c = i2 - j * (HPA / 2);
            Hst[hstage_idx(b, t4, j, tt * 40 + c)] = src[i2];
        }
    }
}

// ---------------- kernel B: one block per (b,t4); out = relu(H @ Thcat) ----------------
// Reads its own staging slots into LDS (barrier), then overwrites exactly those
// t-columns with final output -> no cross-block hazard by construction.
__global__ __launch_bounds__(256, 4) void proj_k(
    const unsigned* __restrict__ Hst,   // staging view of out
    const float* __restrict__ Th,       // (K,F,O)
    const float* __restrict__ ThL,      // (K,F,O)
    float* __restrict__ out)            // (B,N,O,T)
{
    __shared__ __align__(16) unsigned short s_H[144 * BHP + 16];  // +16: A-frag overrun pad

    const int tid = threadIdx.x;
    const int lane = tid & 63;
    const int w = tid >> 6;
    const int lr = lane & 15;
    const int lg = lane >> 4;
    const int kb8 = lg * 8;
    const int ocol = w * 16 + lr;

    const unsigned g = blockIdx.x;
    const unsigned lin = (g & 7u) * (cB * T4 / 8) + (g >> 3);
    const int b = lin / T4, t4 = lin % T4;
    const int t0 = t4 * 4;

    // ---- Theta B-fragments fp16 (c = p*16+f; p0 = Th0+ThL0 merged) ----
    f16x8 bfr[3];
#pragma unroll
    for (int s = 0; s < 3; ++s) {
#pragma unroll
        for (int j = 0; j < 8; ++j) {
            int cc = 32 * s + kb8 + j;
            float v = 0.f;
            if (cc < 80) {
                int p = cc >> 4, f = cc & 15;
                if (p == 0)      v = Th[f * cO + ocol] + ThL[f * cO + ocol];
                else if (p == 1) v = Th[(cF + f) * cO + ocol];
                else if (p == 2) v = Th[(2 * cF + f) * cO + ocol];
                else if (p == 3) v = ThL[(cF + f) * cO + ocol];
                else             v = ThL[(2 * cF + f) * cO + ocol];
            }
            bfr[s][j] = (_Float16)v;
        }
    }

    // ---- load H tile from staging slots into pitch-BHP LDS; pads zero ----
    {
        unsigned* dst = (unsigned*)s_H;
        for (int i2 = tid; i2 < 144 * (BHP / 2); i2 += 256) {
            int r = i2 / (BHP / 2), c = i2 - r * (BHP / 2);
            unsigned v = 0u;
            if (r < 136 && c < 40) {
                int j = r >> 2, tt = r & 3;
                v = Hst[hstage_idx(b, t4, j, tt * 40 + c)];
            }
            dst[i2] = v;
        }
    }
    __syncthreads();

    // ---- MFMA: 9 m-tiles x 3 k-steps per wave ----
    f32x4 acc[9];
#pragma unroll
    for (int mt = 0; mt < 9; ++mt) acc[mt] = (f32x4){0.f, 0.f, 0.f, 0.f};
#pragma unroll
    for (int s = 0; s < 3; ++s) {
#pragma unroll
        for (int mt = 0; mt < 9; ++mt) {
            f16x8 a = *(const f16x8*)&s_H[(mt * 16 + lr) * BHP + kb8 + 32 * s];
            acc[mt] = __builtin_amdgcn_mfma_f32_16x16x32_f16(a, bfr[s], acc[mt], 0, 0, 0);
        }
    }

    // ---- stores: acc[mt] = out[j=4mt+lg, ocol, t0..t0+3] -> one float4 ----
#pragma unroll
    for (int mt = 0; mt < 9; ++mt) {
        int j = 4 * mt + lg;
        if (j < cN) {
            float4 v;
            v.x = fmaxf(acc[mt][0], 0.f);
            v.y = fmaxf(acc[mt][1], 0.f);
            v.z = fmaxf(acc[mt][2], 0.f);
            v.w = fmaxf(acc[mt][3], 0.f);
            *(float4*)&out[(((size_t)b * cN + j) * cO + ocol) * cT + t0] = v;
        }
    }
}

extern "C" void kernel_launch(void* const* d_in, const int* in_sizes, int n_in,
                              void* d_out, int out_size, void* d_ws, size_t ws_size,
                              hipStream_t stream) {
    const float* x    = (const float*)d_in[0];
    const float* st   = (const float*)d_in[1];
    const float* pos  = (const float*)d_in[2];
    const float* dist = (const float*)d_in[3];
    const float* Th   = (const float*)d_in[4];
    const float* ThL  = (const float*)d_in[5];
    float* out = (float*)d_out;
    float* att = (float*)d_ws;                 // 888 KB fp32 (proven ws usage)
    unsigned* Hst = (unsigned*)d_out;          // H staged inside out, race-free layout

    att_softmax_k<<<(cB * cK * cN + 255) / 256, 256, 0, stream>>>(st, att);
    cheb_h_k<<<cB * cT, 256, 0, stream>>>(x, att, pos, dist, Hst);
    proj_k<<<cB * T4, 256, 0, stream>>>(Hst, Th, ThL, out);
}